// Round 12
// baseline (1254.905 us; speedup 1.0000x reference)
//
#include <hip/hip_runtime.h>
#include <hip/hip_bf16.h>
#include <cstdint>
#include <cstddef>

typedef unsigned short ushort_t;
typedef __bf16 bf16x8 __attribute__((ext_vector_type(8)));
typedef float floatx4 __attribute__((ext_vector_type(4)));

#define S_LEN 2048
#define DIN   512
#define DH    512
#define NHEAD 8
#define NBAT  4
#define NBH   32
#define HP    4096   // NHEAD*DH

// ---------- static device workspace ----------
#define MiB (1024ull * 1024ull)
#define WQT_OFF   (0ull)           //  4 MiB  WqT [8][512e][512d] bf16
#define WKT_OFF   (4ull  * MiB)    //  4 MiB
#define WVT_OFF   (8ull  * MiB)    //  4 MiB
#define WPT_OFF   (12ull * MiB)    //  4 MiB  WpT [512][4096] bf16
#define XBF_OFF   (16ull * MiB)    //  8 MiB  x bf16 [4][2048][512]
#define Q_OFF     (24ull * MiB)    // 64 MiB  [32][2048][512] bf16
#define K_OFF     (88ull * MiB)    // 64 MiB
#define VT_OFF    (152ull * MiB)   // 64 MiB  [32][512][2048] bf16
#define O_OFF     (216ull * MiB)   // 64 MiB  [4][2048][4096] bf16 (cat)
#define LSUMP_OFF (280ull * MiB)   //  4 MiB  fp32 [32][16][2048] partial sums
#define P_OFF     (284ull * MiB)   // 128 MiB [16][2048][2048] bf16 (chunk)
#define WS_BYTES  (412ull * MiB)

__device__ __align__(256) unsigned char g_ws[WS_BYTES];

// ---------- helpers ----------
__device__ __forceinline__ ushort_t f2bf(float f) {
  union { float f; uint32_t u; } v; v.f = f;
  uint32_t r = v.u + 0x7fffu + ((v.u >> 16) & 1u);
  return (ushort_t)(r >> 16);
}

typedef __attribute__((address_space(3))) uint32_t lds_uint;
typedef __attribute__((address_space(1))) const uint32_t glb_uint;

__device__ __forceinline__ void async16(void* lds, const void* g) {
  __builtin_amdgcn_global_load_lds((glb_uint*)g, (lds_uint*)lds, 16, 0, 0);
}

// ---------- GEMM core: C[128x128] = A[128xK] * Bt[128xK]^T, bf16, fp32 acc ----
// block = 256 threads (4 waves, 2x2), each wave 64x64 via 4x4 16x16x32 MFMAs.
// Single-barrier double-buffered K-loop (BK=32) + SWIZZLED FETCH:
// DMA pins LDS offset = t*16; we choose WHICH element thread t fetches:
//   row = 16*(t>>6)+(t&15), k = ((t>>4)&3)*8
// so fragment af[i] for lane l sits at wrow*4096 + i*1024 + l*16 (lane-linear
// => ZERO LDS bank conflicts; data identical to the verified fragment:
// at unit u=i*64+l: row=16i+(l&15), k=(l>>4)*8).
// As/Bs: [2 buf][8 KiB] each.
__device__ __forceinline__ void gemm_core(
    const ushort_t* __restrict__ A, const ushort_t* __restrict__ Bt,
    int lda, int ldb, int kdim,
    ushort_t* As, ushort_t* Bs, floatx4 acc[4][4])
{
  const int t = threadIdx.x;
  const int w = t >> 6;
  const int l = t & 63;
  const int wrow = w >> 1, wcol = w & 1;

  const int rowS = 16 * (t >> 6) + (t & 15);     // swizzled fetch row
  const int kelS = ((t >> 4) & 3) * 8;           // swizzled fetch k-offset
  const ushort_t* gA = A + (size_t)rowS * lda + kelS;
  const ushort_t* gB = Bt + (size_t)rowS * ldb + kelS;
  const size_t strideA = (size_t)64 * lda;
  const size_t strideB = (size_t)64 * ldb;
  char* ldsA0 = (char*)As + w * 1024;   // wave-uniform base, buffer 0
  char* ldsB0 = (char*)Bs + w * 1024;

  // prologue: stage window 0 into buffer 0
  async16(ldsA0,        gA);
  async16(ldsA0 + 4096, gA + strideA);
  async16(ldsB0,        gB);
  async16(ldsB0 + 4096, gB + strideB);

#pragma unroll
  for (int i = 0; i < 4; ++i)
#pragma unroll
    for (int j = 0; j < 4; ++j)
      acc[i][j] = (floatx4){0.f, 0.f, 0.f, 0.f};

  const char* rdAw = (const char*)As + wrow * 4096 + l * 16;
  const char* rdBw = (const char*)Bs + wcol * 4096 + l * 16;

  const int nwin = kdim >> 5;
#pragma unroll 1
  for (int k = 0; k < nwin; ++k) {
    __syncthreads();   // drains window-k DMA + prior ds_reads; syncs waves
    const int cur = k & 1;
    if (k + 1 < nwin) {
      const int nxt = cur ^ 1;
      const ushort_t* gA1 = gA + (size_t)(k + 1) * 32;
      const ushort_t* gB1 = gB + (size_t)(k + 1) * 32;
      async16(ldsA0 + nxt * 8192,        gA1);
      async16(ldsA0 + nxt * 8192 + 4096, gA1 + strideA);
      async16(ldsB0 + nxt * 8192,        gB1);
      async16(ldsB0 + nxt * 8192 + 4096, gB1 + strideB);
    }
    const char* rdA = rdAw + cur * 8192;
    const char* rdB = rdBw + cur * 8192;

    bf16x8 af[4], bfr[4];
#pragma unroll
    for (int i = 0; i < 4; ++i) af[i] = *(const bf16x8*)(rdA + i * 1024);
#pragma unroll
    for (int j = 0; j < 4; ++j) bfr[j] = *(const bf16x8*)(rdB + j * 1024);
#pragma unroll
    for (int i = 0; i < 4; ++i)
#pragma unroll
      for (int j = 0; j < 4; ++j)
        acc[i][j] = __builtin_amdgcn_mfma_f32_16x16x32_bf16(af[i], bfr[j], acc[i][j], 0, 0, 0);
  }
}

// ---------- fp32 -> bf16 bulk convert into g_ws ----------
__global__ __launch_bounds__(256) void convert_f32_bf16(
    const float* __restrict__ src, size_t dstOff, int n)
{
  ushort_t* dst = (ushort_t*)(g_ws + dstOff);
  int i = (blockIdx.x * 256 + threadIdx.x) * 4;
  if (i >= n) return;
  float4 v = *(const float4*)(src + i);
  ushort_t o[4] = {f2bf(v.x), f2bf(v.y), f2bf(v.z), f2bf(v.w)};
  *(uint2*)(dst + i) = *(const uint2*)o;
}

// ---------- fp32 [R][C] -> bf16 [C][R] transpose into g_ws, batched over z ----
__global__ __launch_bounds__(256) void transpose_f32_bf16(
    const float* __restrict__ src, size_t dstOff, int R, int C)
{
  __shared__ ushort_t tile[32][33];
  ushort_t* dst = (ushort_t*)(g_ws + dstOff) + (size_t)blockIdx.z * R * C;
  src += (size_t)blockIdx.z * R * C;
  int r0 = blockIdx.y * 32, c0 = blockIdx.x * 32;
  int tx = threadIdx.x & 31, ty = threadIdx.x >> 5;
  for (int i = ty; i < 32; i += 8)
    tile[i][tx] = f2bf(src[(size_t)(r0 + i) * C + (c0 + tx)]);
  __syncthreads();
  for (int i = ty; i < 32; i += 8)
    dst[(size_t)(c0 + i) * R + (r0 + tx)] = tile[tx][i];
}

// ---------- QKV projection, all batches/heads: z in [0,96) ----------
__global__ __launch_bounds__(256) void qkv_gemm(
    const float* __restrict__ bq, const float* __restrict__ bk,
    const float* __restrict__ bv)
{
  __shared__ __align__(16) ushort_t As[2 * 128 * 32], Bs[2 * 128 * 32];
  const int z = blockIdx.z;
  const int bh = z & 31, qkv = z >> 5, b = bh >> 3, h = bh & 7;
  const size_t wOff = (qkv == 0) ? WQT_OFF : (qkv == 1) ? WKT_OFF : WVT_OFF;
  const float* bias = ((qkv == 0) ? bq : (qkv == 1) ? bk : bv) + h * DH;
  const int tileM = blockIdx.y * 128, tileN = blockIdx.x * 128;

  const ushort_t* A  = (const ushort_t*)(g_ws + XBF_OFF)
                       + ((size_t)b * S_LEN + tileM) * DIN;
  const ushort_t* Bt = (const ushort_t*)(g_ws + wOff)
                       + ((size_t)h * DH + tileN) * DIN;
  floatx4 acc[4][4];
  gemm_core(A, Bt, DIN, DIN, DIN, As, Bs, acc);

  ushort_t* Qb = (ushort_t*)(g_ws + Q_OFF);
  ushort_t* Kb = (ushort_t*)(g_ws + K_OFF);
  ushort_t* VT = (ushort_t*)(g_ws + VT_OFF);
  const int t = threadIdx.x, w = t >> 6, l = t & 63;
  const int wrow = w >> 1, wcol = w & 1, l15 = l & 15, lq = l >> 4;
#pragma unroll
  for (int j = 0; j < 4; ++j) {
    const int n = tileN + wcol * 64 + j * 16 + l15;
    const float bsn = bias[n];
#pragma unroll
    for (int i = 0; i < 4; ++i) {
#pragma unroll
      for (int r = 0; r < 4; ++r) {
        const int m = tileM + wrow * 64 + i * 16 + lq * 4 + r;
        const float v = acc[i][j][r] + bsn;
        if (qkv == 0)      Qb[((size_t)bh * S_LEN + m) * DH + n] = f2bf(v);
        else if (qkv == 1) Kb[((size_t)bh * S_LEN + m) * DH + n] = f2bf(v);
        else               VT[((size_t)bh * DH + n) * S_LEN + m] = f2bf(v);
      }
    }
  }
}

// ---------- scores + masked exp + per-N-tile partial row sums ----------
// head chunk [c0, c0+16); lsum_part[bh][xTile][m] (no atomics, no init)
__global__ __launch_bounds__(256) void scores_kernel(
    const int* __restrict__ mask, int c0)
{
  __shared__ __align__(16) ushort_t As[2 * 128 * 32], Bs[2 * 128 * 32];
  const int hl = blockIdx.z, bh = c0 + hl, b = bh >> 3;
  const int tileM = blockIdx.y * 128, tileN = blockIdx.x * 128;

  const ushort_t* A  = (const ushort_t*)(g_ws + Q_OFF)
                       + ((size_t)bh * S_LEN + tileM) * DH;
  const ushort_t* Bt = (const ushort_t*)(g_ws + K_OFF)
                       + ((size_t)bh * S_LEN + tileN) * DH;
  floatx4 acc[4][4];
  gemm_core(A, Bt, DH, DH, DH, As, Bs, acc);

  const float scale = 0.04419417382415922f;  // 1/sqrt(512)
  const int t = threadIdx.x, w = t >> 6, l = t & 63;
  const int wrow = w >> 1, wcol = w & 1, l15 = l & 15, lq = l >> 4;
  ushort_t* Pp = (ushort_t*)(g_ws + P_OFF) + (size_t)hl * S_LEN * S_LEN;
  const int* mask_b = mask + (size_t)b * S_LEN;
  float* lpart = (float*)(g_ws + LSUMP_OFF)
                 + ((size_t)bh * 16 + blockIdx.x) * S_LEN;

  float rsum[4][4];
#pragma unroll
  for (int i = 0; i < 4; ++i)
#pragma unroll
    for (int r = 0; r < 4; ++r) rsum[i][r] = 0.f;

#pragma unroll
  for (int j = 0; j < 4; ++j) {
    const int n = tileN + wcol * 64 + j * 16 + l15;
    const int mv = mask_b[n];
#pragma unroll
    for (int i = 0; i < 4; ++i) {
#pragma unroll
      for (int r = 0; r < 4; ++r) {
        const int m = tileM + wrow * 64 + i * 16 + lq * 4 + r;
        float s = fminf(acc[i][j][r] * scale, 30.f);  // clamp: no inf possible
        const float p = mv ? __expf(s) : 0.f;
        rsum[i][r] += p;
        Pp[(size_t)m * S_LEN + n] = f2bf(p);
      }
    }
  }
  // 16-lane reduce; waves wcol=0/1 cover the two N-halves of this x-tile:
  // combine via one fp32 add by writing halves to distinct slots? No —
  // both wcol halves belong to the SAME x-tile; sum across wcol via LDS.
  __shared__ float red[2][2][64];   // [wrow][wcol][row-slot]
#pragma unroll
  for (int i = 0; i < 4; ++i) {
#pragma unroll
    for (int r = 0; r < 4; ++r) {
      float v = rsum[i][r];
      v += __shfl_xor(v, 1);
      v += __shfl_xor(v, 2);
      v += __shfl_xor(v, 4);
      v += __shfl_xor(v, 8);
      if (l15 == 0) red[wrow][wcol][i * 16 + lq * 4 + r] = v;
    }
  }
  __syncthreads();
  // threads 0..127 finalize one row each: m = tileM + (t>>6 lower?)...
  if (t < 128) {
    const int rr = t & 63, rw = t >> 6;   // rw = wrow, rr = row within 64
    lpart[tileM + rw * 64 + rr] = red[rw][0][rr] + red[rw][1][rr];
  }
}

// ---------- P*V, divide by reduced rowsum, store cat-layout O ----------
__global__ __launch_bounds__(256) void pv_kernel(int c0)
{
  __shared__ __align__(16) ushort_t As[2 * 128 * 32], Bs[2 * 128 * 32];
  __shared__ float lvs[128];
  const int hl = blockIdx.z, bh = c0 + hl, b = bh >> 3, h = bh & 7;
  const int tileM = blockIdx.y * 128, tileN = blockIdx.x * 128;
  const int t = threadIdx.x;

  // reduce the 16 partial sums per row into lvs (gemm's barriers order this)
  const float* lpart = (const float*)(g_ws + LSUMP_OFF) + (size_t)bh * 16 * S_LEN;
  if (t < 128) {
    float s = 0.f;
#pragma unroll
    for (int x = 0; x < 16; ++x) s += lpart[(size_t)x * S_LEN + tileM + t];
    lvs[t] = s;
  }

  const ushort_t* A  = (const ushort_t*)(g_ws + P_OFF)
                       + (size_t)hl * S_LEN * S_LEN + (size_t)tileM * S_LEN;
  const ushort_t* Bt = (const ushort_t*)(g_ws + VT_OFF)
                       + ((size_t)bh * DH + tileN) * S_LEN;
  floatx4 acc[4][4];
  gemm_core(A, Bt, S_LEN, S_LEN, S_LEN, As, Bs, acc);

  ushort_t* Ob = (ushort_t*)(g_ws + O_OFF);
  const int w = t >> 6, l = t & 63;
  const int wrow = w >> 1, wcol = w & 1, l15 = l & 15, lq = l >> 4;
#pragma unroll
  for (int i = 0; i < 4; ++i) {
#pragma unroll
    for (int r = 0; r < 4; ++r) {
      const int mloc = wrow * 64 + i * 16 + lq * 4 + r;
      const int m = tileM + mloc;
      const float lv = lvs[mloc];
      const float inv = (lv > 1e-20f) ? 1.0f / lv : 0.f;  // no inf possible
#pragma unroll
      for (int j = 0; j < 4; ++j) {
        const int n = tileN + wcol * 64 + j * 16 + l15;
        Ob[((size_t)b * S_LEN + m) * HP + h * DH + n] = f2bf(acc[i][j][r] * inv);
      }
    }
  }
}

// ---------- out projection: out_f32[8192][512] = Ob[8192][4096]*WpT^T + bp ----
__global__ __launch_bounds__(256) void proj_kernel(
    const float* __restrict__ bp, float* __restrict__ out)
{
  __shared__ __align__(16) ushort_t As[2 * 128 * 32], Bs[2 * 128 * 32];
  const int tileM = blockIdx.y * 128, tileN = blockIdx.x * 128;

  const ushort_t* A  = (const ushort_t*)(g_ws + O_OFF) + (size_t)tileM * HP;
  const ushort_t* Bt = (const ushort_t*)(g_ws + WPT_OFF) + (size_t)tileN * HP;
  floatx4 acc[4][4];
  gemm_core(A, Bt, HP, HP, HP, As, Bs, acc);

  const int t = threadIdx.x, w = t >> 6, l = t & 63;
  const int wrow = w >> 1, wcol = w & 1, l15 = l & 15, lq = l >> 4;
#pragma unroll
  for (int j = 0; j < 4; ++j) {
    const int n = tileN + wcol * 64 + j * 16 + l15;
    const float bsn = bp[n];
#pragma unroll
    for (int i = 0; i < 4; ++i) {
#pragma unroll
      for (int r = 0; r < 4; ++r) {
        const int m = tileM + wrow * 64 + i * 16 + lq * 4 + r;
        out[(size_t)m * DH + n] = acc[i][j][r] + bsn;   // fp32 store
      }
    }
  }
}

// ---------- host ----------
extern "C" void kernel_launch(void* const* d_in, const int* in_sizes, int n_in,
                              void* d_out, int out_size, void* d_ws, size_t ws_size,
                              hipStream_t stream) {
  // Inputs fp32 (mask int32); OUTPUT fp32.
  const float* x  = (const float*)d_in[0];
  const int*   msk= (const int*)d_in[1];
  const float* Wq = (const float*)d_in[2];
  const float* bq = (const float*)d_in[3];
  const float* Wk = (const float*)d_in[4];
  const float* bk = (const float*)d_in[5];
  const float* Wv = (const float*)d_in[6];
  const float* bv = (const float*)d_in[7];
  const float* Wp = (const float*)d_in[8];
  const float* bp = (const float*)d_in[9];
  float* out = (float*)d_out;

  // x -> bf16 (all batches)
  convert_f32_bf16<<<dim3(NBAT * S_LEN * DIN / 1024), 256, 0, stream>>>(
      x, XBF_OFF, NBAT * S_LEN * DIN);

  // weight transposes (fp32 -> bf16)
  transpose_f32_bf16<<<dim3(16, 16, NHEAD), 256, 0, stream>>>(Wq, WQT_OFF, DIN, DH);
  transpose_f32_bf16<<<dim3(16, 16, NHEAD), 256, 0, stream>>>(Wk, WKT_OFF, DIN, DH);
  transpose_f32_bf16<<<dim3(16, 16, NHEAD), 256, 0, stream>>>(Wv, WVT_OFF, DIN, DH);
  transpose_f32_bf16<<<dim3(16, 128, 1),    256, 0, stream>>>(Wp, WPT_OFF, HP, DH);

  // Q/K/V^T for all 32 (b,h)
  qkv_gemm<<<dim3(DH / 128, S_LEN / 128, 3 * NBH), 256, 0, stream>>>(bq, bk, bv);

  // attention in 2 chunks of 16 heads (P chunk = 128 MiB, L3-friendly)
  for (int c0 = 0; c0 < NBH; c0 += 16) {
    scores_kernel<<<dim3(S_LEN / 128, S_LEN / 128, 16), 256, 0, stream>>>(msk, c0);
    pv_kernel<<<dim3(DH / 128, S_LEN / 128, 16), 256, 0, stream>>>(c0);
  }

  // final projection (fp32 out)
  proj_kernel<<<dim3(DH / 128, (NBAT * S_LEN) / 128), 256, 0, stream>>>(bp, out);
}